// Round 14
// baseline (119.356 us; speedup 1.0000x reference)
//
#include <hip/hip_runtime.h>
#include <stdint.h>

#define NAG   8192
#define NK    4096
#define BLOCK 256
#define ROWS  4
#define CHUNK 128
#define NCK   (NAG / CHUNK)   // 64
#define NCG   (NK  / CHUNK)   // 32
#define AGB   (BLOCK * ROWS)  // 1024
#define NBLK  (NAG / AGB)     // 8
#define NCELL 256             // 16x16 spatial cells over [-4,4]^2
#define RK    0.38f           // KDE cutoff: exp2(-288.5*r^2) < 2^-41
#define RG    0.59f           // GMM cutoff (lw<=0 only shrinks terms)

#define SK_SCALE 16.98643615f
#define SG_SCALE 10.87131904f
#define SG_INV   (0.091984471f)   // 1/SG_SCALE
#define SC_B   (23.5482041f)
#define SC_C   (50569.375f)
#define SC_F   (3355.4432f)

typedef float f32x2 __attribute__((ext_vector_type(2)));

__device__ __forceinline__ f32x2 pk_add(f32x2 a, f32x2 b) {
  f32x2 d; asm("v_pk_add_f32 %0, %1, %2" : "=v"(d) : "v"(a), "v"(b)); return d;
}
__device__ __forceinline__ f32x2 pk_mul(f32x2 a, f32x2 b) {
  f32x2 d; asm("v_pk_mul_f32 %0, %1, %2" : "=v"(d) : "v"(a), "v"(b)); return d;
}
__device__ __forceinline__ f32x2 pk_fma(f32x2 a, f32x2 b, f32x2 c) {
  f32x2 d; asm("v_pk_fma_f32 %0, %1, %2, %3" : "=v"(d) : "v"(a), "v"(b), "v"(c));
  return d;
}
__device__ __forceinline__ f32x2 bcast(float a) { return (f32x2){a, a}; }

__device__ __forceinline__ int cell_of(float x, float y) {
  int xb = (int)((x + 4.0f) * 2.0f);  xb = xb < 0 ? 0 : (xb > 15 ? 15 : xb);
  int yb = (int)((y + 4.0f) * 2.0f);  yb = yb < 0 ? 0 : (yb > 15 ? 15 : yb);
  return yb * 16 + xb;
}

// K0: 2D counting-sort (cells) of agents and means; true bboxes per chunk/block.
__global__ __launch_bounds__(1024) void wm_sort_kernel(
    const float*  __restrict__ t,  const float2* __restrict__ X,
    const float2* __restrict__ m0, const float2* __restrict__ mv,
    const float*  __restrict__ w,
    float2* __restrict__ sX,  int*   __restrict__ sidx,
    float4* __restrict__ sMP, float* __restrict__ sLW,
    float4* __restrict__ cbK, float4* __restrict__ cbG, float4* __restrict__ bbA) {
  __shared__ int hist[NCELL];
  __shared__ int scn[NCELL];
  const int tid  = threadIdx.x;
  const int wid  = tid >> 6, lane = tid & 63;

  // ================= Phase A: agents =================
  if (tid < NCELL) hist[tid] = 0;
  __syncthreads();
  int ac[8]; float2 av[8];
#pragma unroll
  for (int k = 0; k < 8; ++k) {
    const int i = tid + k * 1024;
    const float2 v = X[i];
    ac[k] = cell_of(v.x, v.y);
    av[k] = v;
    atomicAdd(&hist[ac[k]], 1);
  }
  __syncthreads();
  // parallel inclusive scan (Hillis-Steele, 8 steps)
  if (tid < NCELL) scn[tid] = hist[tid];
  __syncthreads();
  for (int off = 1; off < NCELL; off <<= 1) {
    int v = 0;
    if (tid < NCELL && tid >= off) v = scn[tid - off];
    __syncthreads();
    if (tid < NCELL) scn[tid] += v;
    __syncthreads();
  }
  if (tid < NCELL) hist[tid] = scn[tid] - hist[tid];  // exclusive start
  __syncthreads();
#pragma unroll
  for (int k = 0; k < 8; ++k) {
    const int pos = atomicAdd(&hist[ac[k]], 1);
    sX[pos]   = av[k];
    sidx[pos] = tid + k * 1024;
  }
  __syncthreads();
  // per-chunk bboxes: wave w handles chunks w, w+16, w+32, w+48
  for (int c = wid; c < NCK; c += 16) {
    const int b0 = c * CHUNK + lane;
    const float2 a = sX[b0], b = sX[b0 + 64];
    float xlo = fminf(a.x, b.x), xhi = fmaxf(a.x, b.x);
    float ylo = fminf(a.y, b.y), yhi = fmaxf(a.y, b.y);
#pragma unroll
    for (int off = 32; off; off >>= 1) {
      xlo = fminf(xlo, __shfl_xor(xlo, off));
      xhi = fmaxf(xhi, __shfl_xor(xhi, off));
      ylo = fminf(ylo, __shfl_xor(ylo, off));
      yhi = fmaxf(yhi, __shfl_xor(yhi, off));
    }
    if (lane == 0) cbK[c] = make_float4(xlo, xhi, ylo, yhi);
  }
  __syncthreads();
  if (tid < NBLK) {   // block bbox = union of its 8 chunk bboxes
    float4 u = cbK[tid * 8];
#pragma unroll
    for (int j = 1; j < 8; ++j) {
      const float4 v = cbK[tid * 8 + j];
      u.x = fminf(u.x, v.x); u.y = fmaxf(u.y, v.y);
      u.z = fminf(u.z, v.z); u.w = fmaxf(u.w, v.w);
    }
    bbA[tid] = u;
  }
  __syncthreads();

  // ================= Phase B: means =================
  if (tid < NCELL) hist[tid] = 0;
  __syncthreads();
  const float tt = t[0];
  int mc[4]; float4 mp[4]; float ml[4];
#pragma unroll
  for (int k = 0; k < 4; ++k) {
    const int i = tid + k * 1024;
    const float2 a = m0[i], d = mv[i];
    const float mx = __builtin_fmaf(d.x, tt, a.x);
    const float my = __builtin_fmaf(d.y, tt, a.y);
    mc[k] = cell_of(mx, my);
    mp[k] = make_float4(-SG_SCALE * mx, -SG_SCALE * my, d.x, d.y);
    ml[k] = __log2f(w[i]);
    atomicAdd(&hist[mc[k]], 1);
  }
  __syncthreads();
  if (tid < NCELL) scn[tid] = hist[tid];
  __syncthreads();
  for (int off = 1; off < NCELL; off <<= 1) {
    int v = 0;
    if (tid < NCELL && tid >= off) v = scn[tid - off];
    __syncthreads();
    if (tid < NCELL) scn[tid] += v;
    __syncthreads();
  }
  if (tid < NCELL) hist[tid] = scn[tid] - hist[tid];
  __syncthreads();
#pragma unroll
  for (int k = 0; k < 4; ++k) {
    const int pos = atomicAdd(&hist[mc[k]], 1);
    sMP[pos] = mp[k];
    sLW[pos] = ml[k];
  }
  __syncthreads();
  for (int c = wid; c < NCG; c += 16) {
    const int b0 = c * CHUNK + lane;
    const float4 a = sMP[b0], b = sMP[b0 + 64];
    const float ax = -a.x * SG_INV, ay = -a.y * SG_INV;
    const float bx = -b.x * SG_INV, by = -b.y * SG_INV;
    float xlo = fminf(ax, bx), xhi = fmaxf(ax, bx);
    float ylo = fminf(ay, by), yhi = fmaxf(ay, by);
#pragma unroll
    for (int off = 32; off; off >>= 1) {
      xlo = fminf(xlo, __shfl_xor(xlo, off));
      xhi = fmaxf(xhi, __shfl_xor(xhi, off));
      ylo = fminf(ylo, __shfl_xor(ylo, off));
      yhi = fmaxf(yhi, __shfl_xor(yhi, off));
    }
    if (lane == 0) cbG[c] = make_float4(xlo, xhi, ylo, yhi);
  }
}

// K1: pair interactions with block-uniform 2D bbox skip.
__global__ __launch_bounds__(BLOCK) void wm_pair_kernel(
    const float2* __restrict__ sX,
    const float4* __restrict__ sMP, const float* __restrict__ sLW,
    const float4* __restrict__ cbK, const float4* __restrict__ cbG,
    const float4* __restrict__ bbA,
    float4* __restrict__ pK, float4* __restrict__ pG) {
  __shared__ float4 sGP[CHUNK];
  __shared__ float  sWL[CHUNK];

  const int iBase = blockIdx.x * AGB + threadIdx.x;
  const int c = blockIdx.y;
  const float4 bb = bbA[blockIdx.x];   // {xlo,xhi,ylo,yhi}

  if (c < NCK) {
    // ---------------- KDE chunk ----------------
    const float4 cb = cbK[c];
    if (cb.x > bb.y + RK || cb.y < bb.x - RK ||
        cb.z > bb.w + RK || cb.w < bb.z - RK) {
#pragma unroll
      for (int r = 0; r < ROWS; ++r)
        pK[c * NAG + iBase + r * BLOCK] = make_float4(0.f, 0.f, 0.f, 0.f);
      return;
    }
    f32x2* sNP = reinterpret_cast<f32x2*>(sGP);
    const int base = c * CHUNK;
    if (threadIdx.x < CHUNK) {
      const float2 xj = sX[base + threadIdx.x];
      sNP[threadIdx.x] = (f32x2){-SK_SCALE * xj.x, -SK_SCALE * xj.y};
    }
    __syncthreads();

    f32x2 xi[ROWS];
#pragma unroll
    for (int r = 0; r < ROWS; ++r) {
      const float2 v = sX[iBase + r * BLOCK];
      xi[r] = (f32x2){SK_SCALE * v.x, SK_SCALE * v.y};
    }
    float A[ROWS]; f32x2 B[ROWS];
#pragma unroll
    for (int r = 0; r < ROWS; ++r) { A[r] = 0.f; B[r] = (f32x2){0.f, 0.f}; }

#pragma unroll 4
    for (int j = 0; j < CHUNK; ++j) {
      const f32x2 p = sNP[j];
#pragma unroll
      for (int r = 0; r < ROWS; ++r) {
        const f32x2 pd = pk_add(xi[r], p);
        const f32x2 sq = pk_mul(pd, pd);
        const float e  = __builtin_amdgcn_exp2f(-(sq.x + sq.y));
        A[r] += e;
        B[r] = pk_fma(bcast(e), pd, B[r]);
      }
    }
#pragma unroll
    for (int r = 0; r < ROWS; ++r)
      pK[c * NAG + iBase + r * BLOCK] = make_float4(A[r], B[r].x, B[r].y, 0.f);
  } else {
    // ---------------- GMM chunk ----------------
    const int cg = c - NCK;
    const float4 cb = cbG[cg];
    if (cb.x > bb.y + RG || cb.y < bb.x - RG ||
        cb.z > bb.w + RG || cb.w < bb.z - RG) {
#pragma unroll
      for (int r = 0; r < ROWS; ++r)
        pG[cg * NAG + iBase + r * BLOCK] = make_float4(0.f, 0.f, 0.f, 0.f);
      return;
    }
    const int base = cg * CHUNK;
    if (threadIdx.x < CHUNK) {
      sGP[threadIdx.x] = sMP[base + threadIdx.x];
      sWL[threadIdx.x] = sLW[base + threadIdx.x];
    }
    __syncthreads();

    f32x2 xg[ROWS];
#pragma unroll
    for (int r = 0; r < ROWS; ++r) {
      const float2 v = sX[iBase + r * BLOCK];
      xg[r] = (f32x2){SG_SCALE * v.x, SG_SCALE * v.y};
    }
    f32x2 C[ROWS], F[ROWS];
#pragma unroll
    for (int r = 0; r < ROWS; ++r) { C[r] = (f32x2){0.f, 0.f}; F[r] = (f32x2){0.f, 0.f}; }

#pragma unroll 4
    for (int j = 0; j < CHUNK; ++j) {
      const float4 p = sGP[j];
      const float lw = sWL[j];
      const f32x2 nm = (f32x2){p.x, p.y};
      const f32x2 mj = (f32x2){p.z, p.w};
#pragma unroll
      for (int r = 0; r < ROWS; ++r) {
        const f32x2 pd = pk_add(xg[r], nm);
        const f32x2 sq = pk_mul(pd, pd);
        const float gf = __builtin_amdgcn_exp2f(lw - sq.x - sq.y);
        const f32x2 gd = bcast(gf);
        C[r] = pk_fma(gd, pd, C[r]);
        F[r] = pk_fma(gd, mj, F[r]);
      }
    }
#pragma unroll
    for (int r = 0; r < ROWS; ++r)
      pG[cg * NAG + iBase + r * BLOCK] = make_float4(C[r].x, C[r].y, F[r].x, F[r].y);
  }
}

// K2: reduce planes + finalize + scatter to original order.
__global__ __launch_bounds__(64) void wm_final_kernel(
    const float4* __restrict__ pK, const float4* __restrict__ pG,
    const int* __restrict__ sidx, float2* __restrict__ out) {
  const int i = blockIdx.x * 64 + threadIdx.x;
  float A = 0.f, Bx = 0.f, By = 0.f;
#pragma unroll 8
  for (int c = 0; c < NCK; ++c) {
    const float4 v = pK[c * NAG + i];
    A += v.x; Bx += v.y; By += v.z;
  }
  float Cx = 0.f, Cy = 0.f, Fx = 0.f, Fy = 0.f;
#pragma unroll 8
  for (int c = 0; c < NCG; ++c) {
    const float4 v = pG[c * NAG + i];
    Cx += v.x; Cy += v.y; Fx += v.z; Fy += v.w;
  }
  const float invA = 1.0f / A;   // self term e=1 never skipped (d=0)
  const float ox = (SC_B * Bx - SC_C * Cx + SC_F * Fx) * invA;
  const float oy = (SC_B * By - SC_C * Cy + SC_F * Fy) * invA;
  out[sidx[i]] = make_float2(ox, oy);
}

extern "C" void kernel_launch(void* const* d_in, const int* in_sizes, int n_in,
                              void* d_out, int out_size, void* d_ws, size_t ws_size,
                              hipStream_t stream) {
  const float*  t  = (const float*)d_in[0];
  const float2* X  = (const float2*)d_in[1];
  const float2* m0 = (const float2*)d_in[2];
  const float2* mv = (const float2*)d_in[3];
  const float*  w  = (const float*)d_in[4];

  char* p = (char*)d_ws;
  float2* sX   = (float2*)p; p += (size_t)NAG * sizeof(float2);
  int*    sidx = (int*)p;    p += (size_t)NAG * sizeof(int);
  float4* sMP  = (float4*)p; p += (size_t)NK * sizeof(float4);
  float*  sLW  = (float*)p;  p += (size_t)NK * sizeof(float);
  float4* cbK  = (float4*)p; p += (size_t)NCK * sizeof(float4);
  float4* cbG  = (float4*)p; p += (size_t)NCG * sizeof(float4);
  float4* bbA  = (float4*)p; p += (size_t)NBLK * sizeof(float4);
  p = (char*)(((uintptr_t)p + 255) & ~(uintptr_t)255);
  float4* pK   = (float4*)p; p += (size_t)NCK * NAG * sizeof(float4);
  float4* pG   = (float4*)p;

  wm_sort_kernel<<<1, 1024, 0, stream>>>(t, X, m0, mv, w, sX, sidx, sMP, sLW, cbK, cbG, bbA);
  dim3 grid(NBLK, NCK + NCG);   // 8 x 96 = 768 blocks
  wm_pair_kernel<<<grid, BLOCK, 0, stream>>>(sX, sMP, sLW, cbK, cbG, bbA, pK, pG);
  wm_final_kernel<<<NAG / 64, 64, 0, stream>>>(pK, pG, sidx, (float2*)d_out);
}